// Round 6
// baseline (252.334 us; speedup 1.0000x reference)
//
#include <hip/hip_runtime.h>

typedef unsigned int u32;
typedef unsigned short u16;
typedef __attribute__((ext_vector_type(4))) float fx4;
typedef __attribute__((ext_vector_type(8))) short s16x8;
typedef __attribute__((ext_vector_type(4))) u32 u32x4;

#define DD 128
#define KK 1024

__device__ __forceinline__ u16 f2bf(float f) {
  u32 u = __float_as_uint(f);
  return (u16)((u + 0x7FFFu + ((u >> 16) & 1u)) >> 16);
}
__device__ __forceinline__ u32 umin32(u32 a, u32 b) { return a < b ? a : b; }

// ---------------- prep: cbf fp32 -> bf16 (RTN, bit-identical to prior rounds),
// k-major cbt: [lvl(4)][ku(16)][col(1024)][8] u16 (1 MiB). 256 blocks x 64 thr.
// Also zeroes the loss slot in d_out.
extern "C" __global__ __launch_bounds__(64) void rvq_prep(
    const float* __restrict__ cbf, u16* __restrict__ cbt,
    float* __restrict__ lossout) {
  if (blockIdx.x == 0 && threadIdx.x == 0) lossout[0] = 0.f;
  const int cl = threadIdx.x >> 2, dq = threadIdx.x & 3;
  const int cw = blockIdx.x * 16 + cl;
  const int lvl = cw >> 10, colg = cw & 1023;
  const float* src = cbf + (size_t)cw * DD + dq * 32;
  u32x4* dst = (u32x4*)cbt;
#pragma unroll
  for (int k8 = 0; k8 < 4; ++k8) {
    const fx4 a = *(const fx4*)(src + k8 * 8);
    const fx4 b = *(const fx4*)(src + k8 * 8 + 4);
    u32x4 pk;
    pk.x = (u32)f2bf(a[0]) | ((u32)f2bf(a[1]) << 16);
    pk.y = (u32)f2bf(a[2]) | ((u32)f2bf(a[3]) << 16);
    pk.z = (u32)f2bf(b[0]) | ((u32)f2bf(b[1]) << 16);
    pk.w = (u32)f2bf(b[2]) | ((u32)f2bf(b[3]) << 16);
    dst[((lvl * 16 + dq * 4 + k8) * 1024) + colg] = pk;
  }
}

// ---------------- main: 512 blocks x 256 thr; block = 64 rows x 1024 cols.
// 4 waves; each wave holds all 64 rows (afr[4][4]) and scans a 16-col slice of
// each 64-col tile. B streams L2->VGPR with a 4-buffer rotation, prefetch
// distance 3 (12 load-instrs / 12 KB per wave in flight) — no K-loop barriers.
// Prefetch crosses level boundaries (B addresses don't depend on epilogues).
extern "C" __global__ __launch_bounds__(256, 2) void rvq_main(
    const float* __restrict__ x, const float* __restrict__ cbf,
    const u16* __restrict__ cbt, float* __restrict__ yout,
    float* __restrict__ lossacc) {
  __shared__ float Rlds[64][132];  // negated residual; +4 pad
  __shared__ u32 lmin[64][4];      // [row][wave]

  const int tid = threadIdx.x;
  const int wv = tid >> 6, lane = tid & 63;
  const int c = lane & 15, q = lane >> 4;
  const int wvc = wv * 16 + c;
  const int rowbase = blockIdx.x * 64;
  const int rot = (int)((blockIdx.x >> 3) & 15);  // de-lockstep same-XCD L2 streams
  const s16x8* cbase = (const s16x8*)cbt + q * 1024;  // [lvl*16384 + s*4096 + col]

  s16x8 br[4][4];  // rotating B buffers (tile (g)&3), s-indexed
  { // prologue: issue loads for tiles g=0,1,2 of level 0 FIRST (overlap x init)
#pragma unroll
    for (int g = 0; g < 3; ++g) {
      const int cb = (((g + rot) & 15) * 64) + wvc;
#pragma unroll
      for (int s5 = 0; s5 < 4; ++s5) br[g][s5] = cbase[cb + s5 * 4096];
    }
  }

  s16x8 afr[4][4];  // A-frags: afr[t][s] -> rows t*16+c, k = s*32 + q*8 + j
#pragma unroll
  for (int t = 0; t < 4; ++t) {
    const float* xr = x + (size_t)(rowbase + t * 16 + c) * DD + q * 8;
#pragma unroll
    for (int s = 0; s < 4; ++s) {
      const fx4 a = *(const fx4*)(xr + s * 32);
      const fx4 b = *(const fx4*)(xr + s * 32 + 4);
      fx4 na, nb;
      s16x8 af;
#pragma unroll
      for (int j = 0; j < 4; ++j) { na[j] = -a[j]; nb[j] = -b[j]; }
#pragma unroll
      for (int j = 0; j < 4; ++j) { af[j] = (short)f2bf(na[j]); af[4 + j] = (short)f2bf(nb[j]); }
      afr[t][s] = af;
      if (t == wv) {
        *(fx4*)&Rlds[t * 16 + c][s * 32 + q * 8] = na;
        *(fx4*)&Rlds[t * 16 + c][s * 32 + q * 8 + 4] = nb;
      }
    }
  }

  u32 run[4][4];
#pragma unroll
  for (int t = 0; t < 4; ++t)
#pragma unroll
    for (int r = 0; r < 4; ++r) run[t][r] = 0xFFFFFFFFu;

  float lsum = 0.f;

#pragma unroll 1
  for (int lvl = 0; lvl < 4; ++lvl) {
    // acc = 0.75 - r.c in (0.625,0.875) ⊂ [0.5,1): single exponent -> monotone
    // key = (bits(acc)<<10) + col - 2^31; ties -> lowest col (matches argmin).
#define KSTEP(CT)                                                                  \
  {                                                                                \
    if ((CT) < 13 || lvl < 3) { /* prefetch tile g+3 (may cross level) */          \
      const int g2 = lvl * 16 + (CT) + 3;                                          \
      const int cb2 = (g2 >> 4) * 16384 + ((((g2) & 15) + rot) & 15) * 64 + wvc;   \
      _Pragma("unroll") for (int s5 = 0; s5 < 4; ++s5)                             \
          br[((CT) + 3) & 3][s5] = cbase[cb2 + s5 * 4096];                         \
    }                                                                              \
    const u32 kadd = (u32)(((((CT) + rot) & 15) * 64) + wvc) - 0x80000000u;        \
    fx4 ac0 = {0.75f, 0.75f, 0.75f, 0.75f};                                        \
    fx4 ac1 = ac0, ac2 = ac0, ac3 = ac0;                                           \
    _Pragma("unroll") for (int s5 = 0; s5 < 4; ++s5) {                             \
      const s16x8 bfrag = br[(CT) & 3][s5];                                        \
      ac0 = __builtin_amdgcn_mfma_f32_16x16x32_bf16(afr[0][s5], bfrag, ac0, 0, 0, 0); \
      ac1 = __builtin_amdgcn_mfma_f32_16x16x32_bf16(afr[1][s5], bfrag, ac1, 0, 0, 0); \
      ac2 = __builtin_amdgcn_mfma_f32_16x16x32_bf16(afr[2][s5], bfrag, ac2, 0, 0, 0); \
      ac3 = __builtin_amdgcn_mfma_f32_16x16x32_bf16(afr[3][s5], bfrag, ac3, 0, 0, 0); \
    }                                                                              \
    _Pragma("unroll") for (int r5 = 0; r5 < 4; ++r5) {                             \
      run[0][r5] = umin32(run[0][r5], (__float_as_uint(ac0[r5]) << 10) + kadd);    \
      run[1][r5] = umin32(run[1][r5], (__float_as_uint(ac1[r5]) << 10) + kadd);    \
      run[2][r5] = umin32(run[2][r5], (__float_as_uint(ac2[r5]) << 10) + kadd);    \
      run[3][r5] = umin32(run[3][r5], (__float_as_uint(ac3[r5]) << 10) + kadd);    \
    }                                                                              \
  }
    KSTEP(0)  KSTEP(1)  KSTEP(2)  KSTEP(3)  KSTEP(4)  KSTEP(5)  KSTEP(6)  KSTEP(7)
    KSTEP(8)  KSTEP(9)  KSTEP(10) KSTEP(11) KSTEP(12) KSTEP(13) KSTEP(14) KSTEP(15)
#undef KSTEP

    // reduce over the 16 c-lanes (row lives on q*4+r within tile t)
#pragma unroll
    for (int m = 1; m < 16; m <<= 1)
#pragma unroll
      for (int t = 0; t < 4; ++t)
#pragma unroll
        for (int r = 0; r < 4; ++r)
          run[t][r] = umin32(run[t][r], (u32)__shfl_xor((int)run[t][r], m, 64));
    if (c == 0) {
#pragma unroll
      for (int t = 0; t < 4; ++t)
#pragma unroll
        for (int r = 0; r < 4; ++r)
          lmin[t * 16 + q * 4 + r][wv] = run[t][r];
    }
    __syncthreads();  // lmin complete (drains the 3 in-flight prefetches too — bounded cost)

    // update own rows: row = wv*16 + c, dims q*32..q*32+31 (exact fp32 codebook)
    const int row = wv * 16 + c;
    const u32x4 p = *(const u32x4*)&lmin[row][0];
    const u32 pm = umin32(umin32(p.x, p.y), umin32(p.z, p.w));
    const int col = (int)(pm & 1023u);
    const float* qp = cbf + ((size_t)lvl * KK + col) * DD + q * 32;
    float* Rr = &Rlds[row][q * 32];
#pragma unroll
    for (int k4 = 0; k4 < 8; ++k4) {
      fx4 rv = *(const fx4*)(Rr + k4 * 4);
      const fx4 qv = *(const fx4*)(qp + k4 * 4);
#pragma unroll
      for (int j = 0; j < 4; ++j) { rv[j] += qv[j]; lsum = fmaf(rv[j], rv[j], lsum); }
      *(fx4*)(Rr + k4 * 4) = rv;
    }
    if (lvl < 3) {
      __syncthreads();  // all rows' new residuals visible; orders lmin vs next level
#pragma unroll
      for (int t = 0; t < 4; ++t)
#pragma unroll
        for (int s = 0; s < 4; ++s) {
          const fx4 r0 = *(const fx4*)&Rlds[t * 16 + c][s * 32 + q * 8];
          const fx4 r1 = *(const fx4*)&Rlds[t * 16 + c][s * 32 + q * 8 + 4];
          s16x8 af;
#pragma unroll
          for (int j = 0; j < 4; ++j) { af[j] = (short)f2bf(r0[j]); af[4 + j] = (short)f2bf(r1[j]); }
          afr[t][s] = af;
        }
#pragma unroll
      for (int t = 0; t < 4; ++t)
#pragma unroll
        for (int r = 0; r < 4; ++r) run[t][r] = 0xFFFFFFFFu;
    }
  }

  // ---- coalesced y epilogue: wave reads its OWN rows from Rlds (same-wave
  // ds ordering, no barrier needed) and streams y = x + R, 1 KB per instr.
#pragma unroll
  for (int pass = 0; pass < 8; ++pass) {
    const int row = wv * 16 + pass * 2 + (lane >> 5);
    const int coff = (lane & 31) * 4;
    const fx4 rv = *(const fx4*)&Rlds[row][coff];
    const size_t gb = (size_t)(rowbase + row) * DD + coff;
    const fx4 xv = *(const fx4*)(x + gb);
    fx4 yv;
#pragma unroll
    for (int j = 0; j < 4; ++j) yv[j] = xv[j] + rv[j];
    __builtin_nontemporal_store(yv, (fx4*)(yout + gb));
  }

#pragma unroll
  for (int m = 32; m >= 1; m >>= 1) lsum += __shfl_xor(lsum, m, 64);
  if (lane == 0) atomicAdd(lossacc, lsum * (1.25f / 4194304.f));  // 1.25/(N*D)
}

extern "C" void kernel_launch(void* const* d_in, const int* in_sizes, int n_in,
                              void* d_out, int out_size, void* d_ws, size_t ws_size,
                              hipStream_t stream) {
  const float* x = (const float*)d_in[0];     // [32768,128]
  const float* cbf = (const float*)d_in[1];   // [4,1024,128]
  float* y = (float*)d_out;
  float* lossout = y + (out_size - 1);
  u16* cbt = (u16*)d_ws;                      // 1 MiB k-major bf16 codebook

  rvq_prep<<<256, 64, 0, stream>>>(cbf, cbt, lossout);
  rvq_main<<<512, 256, 0, stream>>>(x, cbf, cbt, y, lossout);
}